// Round 1
// baseline (2984.091 us; speedup 1.0000x reference)
//
#include <hip/hip_runtime.h>

constexpr int N_NODES = 50000;
constexpr int IN_C    = 128;
constexpr int HID_C   = 128;
constexpr int OUT_C   = 64;
constexpr int N_EDGES = 800000;
constexpr int N_LABEL = 200000;
constexpr float BN_EPS = 1e-5f;

// ---------------------------------------------------------------------------
// degree count: cnt[dst] += 1
__global__ void count_kernel(const int* __restrict__ dst, float* __restrict__ cnt) {
    int e = blockIdx.x * blockDim.x + threadIdx.x;
    if (e < N_EDGES) atomicAdd(&cnt[dst[e]], 1.0f);
}

// ---------------------------------------------------------------------------
// scatter-add aggregation: agg[dst] += x[src]; C channels, C/4 threads/edge
template <int C>
__global__ void aggregate_kernel(const int* __restrict__ src, const int* __restrict__ dst,
                                 const float* __restrict__ x, float* __restrict__ agg) {
    constexpr int TPE = C / 4;
    long long gid = (long long)blockIdx.x * blockDim.x + threadIdx.x;
    int e = (int)(gid / TPE);
    int c = (int)(gid % TPE) * 4;
    if (e >= N_EDGES) return;
    int s = src[e];
    int d = dst[e];
    const float4 v = *reinterpret_cast<const float4*>(x + (long long)s * C + c);
    float* a = agg + (long long)d * C + c;
    atomicAdd(a + 0, v.x);
    atomicAdd(a + 1, v.y);
    atomicAdd(a + 2, v.z);
    atomicAdd(a + 3, v.w);
}

// ---------------------------------------------------------------------------
// h = (agg/max(cnt,1)) @ Wl + x @ Wr + b        [N,128] @ [128,128]
// block: 256 threads -> 8 rows x 128 cols, each thread 4 rows
__global__ __launch_bounds__(256) void gemm1_kernel(
    const float* __restrict__ agg, const float* __restrict__ cnt,
    const float* __restrict__ x,
    const float* __restrict__ Wl, const float* __restrict__ Wr,
    const float* __restrict__ bias, float* __restrict__ out) {
    __shared__ float sm[8][128];
    __shared__ float sx[8][128];
    int row0 = blockIdx.x * 8;
    for (int i = threadIdx.x; i < 8 * 128; i += 256) {
        int r = i >> 7, c = i & 127;
        int row = row0 + r;
        float m = 0.f, xv = 0.f;
        if (row < N_NODES) {
            float inv = 1.0f / fmaxf(cnt[row], 1.0f);
            m  = agg[(long long)row * 128 + c] * inv;
            xv = x[(long long)row * 128 + c];
        }
        sm[r][c] = m;
        sx[r][c] = xv;
    }
    __syncthreads();
    int col = threadIdx.x & 127;
    int grp = threadIdx.x >> 7;     // 0..1, rows grp*4 .. grp*4+3
    int rb  = grp * 4;
    float bb = bias[col];
    float acc0 = bb, acc1 = bb, acc2 = bb, acc3 = bb;
    #pragma unroll 4
    for (int k = 0; k < 128; ++k) {
        float wl = Wl[k * 128 + col];
        float wr = Wr[k * 128 + col];
        acc0 += sm[rb + 0][k] * wl + sx[rb + 0][k] * wr;
        acc1 += sm[rb + 1][k] * wl + sx[rb + 1][k] * wr;
        acc2 += sm[rb + 2][k] * wl + sx[rb + 2][k] * wr;
        acc3 += sm[rb + 3][k] * wl + sx[rb + 3][k] * wr;
    }
    float accs[4] = {acc0, acc1, acc2, acc3};
    #pragma unroll
    for (int r = 0; r < 4; ++r) {
        int row = row0 + rb + r;
        if (row < N_NODES) out[(long long)row * 128 + col] = accs[r];
    }
}

// ---------------------------------------------------------------------------
// z = (agg/max(cnt,1)) @ Wl + h @ Wr + b        [N,128] @ [128,64]
// block: 256 threads -> 16 rows x 64 cols, each thread 4 rows
__global__ __launch_bounds__(256) void gemm2_kernel(
    const float* __restrict__ agg, const float* __restrict__ cnt,
    const float* __restrict__ h,
    const float* __restrict__ Wl, const float* __restrict__ Wr,
    const float* __restrict__ bias, float* __restrict__ z) {
    __shared__ float sm[16][128];
    __shared__ float sx[16][128];
    int row0 = blockIdx.x * 16;
    for (int i = threadIdx.x; i < 16 * 128; i += 256) {
        int r = i >> 7, c = i & 127;
        int row = row0 + r;
        float m = 0.f, xv = 0.f;
        if (row < N_NODES) {
            float inv = 1.0f / fmaxf(cnt[row], 1.0f);
            m  = agg[(long long)row * 128 + c] * inv;
            xv = h[(long long)row * 128 + c];
        }
        sm[r][c] = m;
        sx[r][c] = xv;
    }
    __syncthreads();
    int col = threadIdx.x & 63;
    int grp = threadIdx.x >> 6;     // 0..3, rows grp*4 .. grp*4+3
    int rb  = grp * 4;
    float bb = bias[col];
    float acc0 = bb, acc1 = bb, acc2 = bb, acc3 = bb;
    #pragma unroll 4
    for (int k = 0; k < 128; ++k) {
        float wl = Wl[k * 64 + col];
        float wr = Wr[k * 64 + col];
        acc0 += sm[rb + 0][k] * wl + sx[rb + 0][k] * wr;
        acc1 += sm[rb + 1][k] * wl + sx[rb + 1][k] * wr;
        acc2 += sm[rb + 2][k] * wl + sx[rb + 2][k] * wr;
        acc3 += sm[rb + 3][k] * wl + sx[rb + 3][k] * wr;
    }
    float accs[4] = {acc0, acc1, acc2, acc3};
    #pragma unroll
    for (int r = 0; r < 4; ++r) {
        int row = row0 + rb + r;
        if (row < N_NODES) z[(long long)row * 64 + col] = accs[r];
    }
}

// ---------------------------------------------------------------------------
// BN stats: sums[c] = sum_r h[r][c], sums[128+c] = sum_r h[r][c]^2
__global__ void bn_stats_kernel(const float* __restrict__ h, float* __restrict__ sums) {
    int c = threadIdx.x & 127;
    int r0 = blockIdx.x * 2 + (threadIdx.x >> 7);
    int stride = gridDim.x * 2;
    float s = 0.f, sq = 0.f;
    for (int r = r0; r < N_NODES; r += stride) {
        float v = h[(long long)r * 128 + c];
        s += v;
        sq += v * v;
    }
    atomicAdd(&sums[c], s);
    atomicAdd(&sums[128 + c], sq);
}

// scale/shift: ss[c] = gamma*rsqrt(var+eps); ss[128+c] = beta - mu*scale
__global__ void bn_finalize_kernel(const float* __restrict__ sums,
                                   const float* __restrict__ gamma,
                                   const float* __restrict__ beta,
                                   float* __restrict__ ss) {
    int c = threadIdx.x;
    float mu  = sums[c] * (1.0f / N_NODES);
    float var = sums[128 + c] * (1.0f / N_NODES) - mu * mu;
    float sc = gamma[c] * rsqrtf(var + BN_EPS);
    ss[c] = sc;
    ss[128 + c] = beta[c] - mu * sc;
}

// h = relu(h*scale + shift), in place, float4
__global__ void bn_relu_kernel(float* __restrict__ h, const float* __restrict__ ss) {
    long long gid = (long long)blockIdx.x * blockDim.x + threadIdx.x;
    if (gid >= (long long)N_NODES * 128 / 4) return;
    long long i4 = gid * 4;
    int c = (int)(i4 & 127);
    float4 v = *reinterpret_cast<const float4*>(h + i4);
    v.x = fmaxf(v.x * ss[c + 0] + ss[128 + c + 0], 0.f);
    v.y = fmaxf(v.y * ss[c + 1] + ss[128 + c + 1], 0.f);
    v.z = fmaxf(v.z * ss[c + 2] + ss[128 + c + 2], 0.f);
    v.w = fmaxf(v.w * ss[c + 3] + ss[128 + c + 3], 0.f);
    *reinterpret_cast<float4*>(h + i4) = v;
}

// ---------------------------------------------------------------------------
// out[l] = dot(z[src_l], z[dst_l]) over 64 channels; 16 lanes per label
__global__ void edge_dot_kernel(const int* __restrict__ eli, const float* __restrict__ z,
                                float* __restrict__ out) {
    long long gid = (long long)blockIdx.x * blockDim.x + threadIdx.x;
    int l = (int)(gid >> 4);
    int lane = (int)(gid & 15);
    if (l >= N_LABEL) return;
    int s = eli[l];
    int d = eli[N_LABEL + l];
    const float4 a = *reinterpret_cast<const float4*>(z + (long long)s * 64 + lane * 4);
    const float4 b = *reinterpret_cast<const float4*>(z + (long long)d * 64 + lane * 4);
    float p = a.x * b.x + a.y * b.y + a.z * b.z + a.w * b.w;
    p += __shfl_down(p, 8, 16);
    p += __shfl_down(p, 4, 16);
    p += __shfl_down(p, 2, 16);
    p += __shfl_down(p, 1, 16);
    if (lane == 0) out[l] = p;
}

// ---------------------------------------------------------------------------
extern "C" void kernel_launch(void* const* d_in, const int* in_sizes, int n_in,
                              void* d_out, int out_size, void* d_ws, size_t ws_size,
                              hipStream_t stream) {
    const float* x     = (const float*)d_in[0];
    const int*   ei    = (const int*)d_in[1];   // [2, 800000]: row0 src, row1 dst
    const int*   eli   = (const int*)d_in[2];   // [2, 200000]
    const float* W1l   = (const float*)d_in[3];
    const float* W1r   = (const float*)d_in[4];
    const float* b1    = (const float*)d_in[5];
    const float* gamma = (const float*)d_in[6];
    const float* beta  = (const float*)d_in[7];
    const float* W2l   = (const float*)d_in[8];
    const float* W2r   = (const float*)d_in[9];
    const float* b2    = (const float*)d_in[10];
    float* out = (float*)d_out;

    float* ws   = (float*)d_ws;
    float* cnt  = ws;                    // 50000 (padded to 50048)
    float* agg  = ws + 50048;            // 6,400,000
    float* h    = agg + 6400000;         // 6,400,000  (hpre, then h in place)
    float* z    = h + 6400000;           // 3,200,000
    float* sums = z + 3200000;           // 256
    float* ss   = sums + 256;            // 256

    const int* src  = ei;
    const int* dstv = ei + N_EDGES;

    // zero cnt + agg (contiguous) and BN accumulators
    hipMemsetAsync(cnt, 0, (size_t)(50048 + 6400000) * sizeof(float), stream);
    hipMemsetAsync(sums, 0, 256 * sizeof(float), stream);

    count_kernel<<<(N_EDGES + 255) / 256, 256, 0, stream>>>(dstv, cnt);

    // ---- conv1 ----
    aggregate_kernel<128><<<(N_EDGES * 32 + 255) / 256, 256, 0, stream>>>(src, dstv, x, agg);
    gemm1_kernel<<<(N_NODES + 7) / 8, 256, 0, stream>>>(agg, cnt, x, W1l, W1r, b1, h);

    // ---- batchnorm + relu ----
    bn_stats_kernel<<<500, 256, 0, stream>>>(h, sums);
    bn_finalize_kernel<<<1, 128, 0, stream>>>(sums, gamma, beta, ss);
    bn_relu_kernel<<<(N_NODES * 128 / 4 + 255) / 256, 256, 0, stream>>>(h, ss);

    // ---- conv2 ----
    hipMemsetAsync(agg, 0, (size_t)6400000 * sizeof(float), stream);
    aggregate_kernel<128><<<(N_EDGES * 32 + 255) / 256, 256, 0, stream>>>(src, dstv, h, agg);
    gemm2_kernel<<<(N_NODES + 15) / 16, 256, 0, stream>>>(agg, cnt, h, W2l, W2r, b2, z);

    // ---- edge dot readout ----
    edge_dot_kernel<<<((long long)N_LABEL * 16 + 255) / 256, 256, 0, stream>>>(eli, z, out);
}

// Round 2
// 997.111 us; speedup vs baseline: 2.9927x; 2.9927x over previous
//
#include <hip/hip_runtime.h>

constexpr int N_NODES = 50000;
constexpr int IN_C    = 128;
constexpr int HID_C   = 128;
constexpr int OUT_C   = 64;
constexpr int N_EDGES = 800000;
constexpr int N_LABEL = 200000;
constexpr float BN_EPS = 1e-5f;

// ---------------------------------------------------------------------------
// CSR build step 1: histogram of dst
__global__ void hist_kernel(const int* __restrict__ dst, int* __restrict__ deg) {
    int e = blockIdx.x * blockDim.x + threadIdx.x;
    if (e < N_EDGES) atomicAdd(&deg[dst[e]], 1);
}

// CSR build step 2: exclusive scan of deg -> off, copy to cursor. Single block.
__global__ void scan_kernel(const int* __restrict__ deg, int* __restrict__ off,
                            int* __restrict__ cursor) {
    __shared__ int tsum[256];
    int tid = threadIdx.x;
    constexpr int CH = (N_NODES + 255) / 256;   // 196
    int beg = tid * CH;
    int end = min(beg + CH, N_NODES);
    int s = 0;
    for (int i = beg; i < end; ++i) s += deg[i];
    tsum[tid] = s;
    __syncthreads();
    // Hillis-Steele inclusive scan over 256 thread sums
    for (int o = 1; o < 256; o <<= 1) {
        int v = tsum[tid];
        int add = (tid >= o) ? tsum[tid - o] : 0;
        __syncthreads();
        tsum[tid] = v + add;
        __syncthreads();
    }
    int run = (tid == 0) ? 0 : tsum[tid - 1];
    for (int i = beg; i < end; ++i) {
        off[i] = run;
        cursor[i] = run;
        run += deg[i];
    }
    if (tid == 255) off[N_NODES] = run;   // == N_EDGES
}

// CSR build step 3: scatter src ids into csr order
__global__ void scatter_kernel(const int* __restrict__ src, const int* __restrict__ dst,
                               int* __restrict__ cursor, int* __restrict__ csr_src) {
    int e = blockIdx.x * blockDim.x + threadIdx.x;
    if (e < N_EDGES) {
        int pos = atomicAdd(&cursor[dst[e]], 1);
        csr_src[pos] = src[e];
    }
}

// ---------------------------------------------------------------------------
// GEMM1 dual: y1 = x @ W1l ; h = x @ W1r + b1     (x:[N,128], W:[128,128])
// block: 16 rows staged in LDS; 256 threads; col=tid&127, 8 rows/thread
__global__ __launch_bounds__(256) void gemm1_dual(
    const float* __restrict__ x, const float* __restrict__ Wl,
    const float* __restrict__ Wr, const float* __restrict__ bias,
    float* __restrict__ y1, float* __restrict__ h) {
    __shared__ float sx[16][128];
    int row0 = blockIdx.x * 16;
    for (int i = threadIdx.x; i < 16 * 128; i += 256) {
        int r = i >> 7, c = i & 127;
        int row = row0 + r;
        sx[r][c] = (row < N_NODES) ? x[(long long)row * 128 + c] : 0.f;
    }
    __syncthreads();
    int col = threadIdx.x & 127;
    int rb  = (threadIdx.x >> 7) * 8;    // 0 or 8
    float bb = bias[col];
    float accL[8] = {0.f, 0.f, 0.f, 0.f, 0.f, 0.f, 0.f, 0.f};
    float accR[8];
    #pragma unroll
    for (int r = 0; r < 8; ++r) accR[r] = bb;
    for (int k4 = 0; k4 < 128; k4 += 4) {
        float4 xv[8];
        #pragma unroll
        for (int r = 0; r < 8; ++r)
            xv[r] = *reinterpret_cast<const float4*>(&sx[rb + r][k4]);
        #pragma unroll
        for (int kk = 0; kk < 4; ++kk) {
            float wl = Wl[(k4 + kk) * 128 + col];
            float wr = Wr[(k4 + kk) * 128 + col];
            #pragma unroll
            for (int r = 0; r < 8; ++r) {
                float xs = (&xv[r].x)[kk];
                accL[r] += xs * wl;
                accR[r] += xs * wr;
            }
        }
    }
    #pragma unroll
    for (int r = 0; r < 8; ++r) {
        int row = row0 + rb + r;
        if (row < N_NODES) {
            y1[(long long)row * 128 + col] = accL[r];
            h [(long long)row * 128 + col] = accR[r];
        }
    }
}

// ---------------------------------------------------------------------------
// conv1 aggregate: h[n] += mean_{s in N(n)} y1[s]   (128 ch, wave per node)
__global__ __launch_bounds__(256) void agg_mean_add_128(
    const int* __restrict__ off, const int* __restrict__ csr_src,
    const float* __restrict__ y, float* __restrict__ h) {
    int node = blockIdx.x * 4 + (threadIdx.x >> 6);
    if (node >= N_NODES) return;
    int lane = threadIdx.x & 63;
    int beg = off[node], end = off[node + 1];
    float ax0 = 0.f, ay0 = 0.f, ax1 = 0.f, ay1 = 0.f;
    int i = beg;
    for (; i + 1 < end; i += 2) {
        int s0 = csr_src[i];
        int s1 = csr_src[i + 1];
        float2 v0 = *reinterpret_cast<const float2*>(y + (long long)s0 * 128 + lane * 2);
        float2 v1 = *reinterpret_cast<const float2*>(y + (long long)s1 * 128 + lane * 2);
        ax0 += v0.x; ay0 += v0.y;
        ax1 += v1.x; ay1 += v1.y;
    }
    if (i < end) {
        int s0 = csr_src[i];
        float2 v0 = *reinterpret_cast<const float2*>(y + (long long)s0 * 128 + lane * 2);
        ax0 += v0.x; ay0 += v0.y;
    }
    float inv = (end > beg) ? 1.0f / (float)(end - beg) : 0.f;
    float2* hp = reinterpret_cast<float2*>(h + (long long)node * 128 + lane * 2);
    float2 hv = *hp;
    hv.x += (ax0 + ax1) * inv;
    hv.y += (ay0 + ay1) * inv;
    *hp = hv;
}

// ---------------------------------------------------------------------------
// BN stats: sums[c] = sum_r h[r][c], sums[128+c] = sum_r h[r][c]^2
__global__ void bn_stats_kernel(const float* __restrict__ h, float* __restrict__ sums) {
    int c = threadIdx.x & 127;
    int r0 = blockIdx.x * 2 + (threadIdx.x >> 7);
    int stride = gridDim.x * 2;
    float s = 0.f, sq = 0.f;
    for (int r = r0; r < N_NODES; r += stride) {
        float v = h[(long long)r * 128 + c];
        s += v;
        sq += v * v;
    }
    atomicAdd(&sums[c], s);
    atomicAdd(&sums[128 + c], sq);
}

// scale/shift: ss[c] = gamma*rsqrt(var+eps); ss[128+c] = beta - mu*scale
__global__ void bn_finalize_kernel(const float* __restrict__ sums,
                                   const float* __restrict__ gamma,
                                   const float* __restrict__ beta,
                                   float* __restrict__ ss) {
    int c = threadIdx.x;
    float mu  = sums[c] * (1.0f / N_NODES);
    float var = sums[128 + c] * (1.0f / N_NODES) - mu * mu;
    float sc = gamma[c] * rsqrtf(var + BN_EPS);
    ss[c] = sc;
    ss[128 + c] = beta[c] - mu * sc;
}

// ---------------------------------------------------------------------------
// GEMM2 dual with fused BN+ReLU on the staged load:
//   hb = relu(h*scale + shift);  t2l = hb @ W2l ; t2r = hb @ W2r + b2
// block: 16 rows; 256 threads; col=tid&63, 4 rows/thread
__global__ __launch_bounds__(256) void gemm2_dual(
    const float* __restrict__ h, const float* __restrict__ ss,
    const float* __restrict__ Wl, const float* __restrict__ Wr,
    const float* __restrict__ bias, float* __restrict__ t2l, float* __restrict__ t2r) {
    __shared__ float sx[16][128];
    int row0 = blockIdx.x * 16;
    for (int i = threadIdx.x; i < 16 * 128; i += 256) {
        int r = i >> 7, c = i & 127;
        int row = row0 + r;
        float v = (row < N_NODES) ? h[(long long)row * 128 + c] : 0.f;
        sx[r][c] = fmaxf(v * ss[c] + ss[128 + c], 0.f);
    }
    __syncthreads();
    int col = threadIdx.x & 63;
    int rb  = (threadIdx.x >> 6) * 4;    // 0,4,8,12
    float bb = bias[col];
    float accL[4] = {0.f, 0.f, 0.f, 0.f};
    float accR[4];
    #pragma unroll
    for (int r = 0; r < 4; ++r) accR[r] = bb;
    for (int k4 = 0; k4 < 128; k4 += 4) {
        float4 xv[4];
        #pragma unroll
        for (int r = 0; r < 4; ++r)
            xv[r] = *reinterpret_cast<const float4*>(&sx[rb + r][k4]);
        #pragma unroll
        for (int kk = 0; kk < 4; ++kk) {
            float wl = Wl[(k4 + kk) * 64 + col];
            float wr = Wr[(k4 + kk) * 64 + col];
            #pragma unroll
            for (int r = 0; r < 4; ++r) {
                float xs = (&xv[r].x)[kk];
                accL[r] += xs * wl;
                accR[r] += xs * wr;
            }
        }
    }
    #pragma unroll
    for (int r = 0; r < 4; ++r) {
        int row = row0 + rb + r;
        if (row < N_NODES) {
            t2l[(long long)row * 64 + col] = accL[r];
            t2r[(long long)row * 64 + col] = accR[r];
        }
    }
}

// ---------------------------------------------------------------------------
// conv2 aggregate: z[n] = mean_{s in N(n)} t2l[s] + t2r[n]   (64 ch, wave/node)
__global__ __launch_bounds__(256) void agg_mean_add_64(
    const int* __restrict__ off, const int* __restrict__ csr_src,
    const float* __restrict__ t2l, const float* __restrict__ t2r,
    float* __restrict__ z) {
    int node = blockIdx.x * 4 + (threadIdx.x >> 6);
    if (node >= N_NODES) return;
    int lane = threadIdx.x & 63;
    int beg = off[node], end = off[node + 1];
    float a0 = 0.f, a1 = 0.f;
    int i = beg;
    for (; i + 1 < end; i += 2) {
        int s0 = csr_src[i];
        int s1 = csr_src[i + 1];
        a0 += t2l[(long long)s0 * 64 + lane];
        a1 += t2l[(long long)s1 * 64 + lane];
    }
    if (i < end) a0 += t2l[(long long)csr_src[i] * 64 + lane];
    float inv = (end > beg) ? 1.0f / (float)(end - beg) : 0.f;
    z[(long long)node * 64 + lane] = t2r[(long long)node * 64 + lane] + (a0 + a1) * inv;
}

// ---------------------------------------------------------------------------
// out[l] = dot(z[src_l], z[dst_l]) over 64 channels; 16 lanes per label
__global__ void edge_dot_kernel(const int* __restrict__ eli, const float* __restrict__ z,
                                float* __restrict__ out) {
    long long gid = (long long)blockIdx.x * blockDim.x + threadIdx.x;
    int l = (int)(gid >> 4);
    int lane = (int)(gid & 15);
    if (l >= N_LABEL) return;
    int s = eli[l];
    int d = eli[N_LABEL + l];
    const float4 a = *reinterpret_cast<const float4*>(z + (long long)s * 64 + lane * 4);
    const float4 b = *reinterpret_cast<const float4*>(z + (long long)d * 64 + lane * 4);
    float p = a.x * b.x + a.y * b.y + a.z * b.z + a.w * b.w;
    p += __shfl_down(p, 8, 16);
    p += __shfl_down(p, 4, 16);
    p += __shfl_down(p, 2, 16);
    p += __shfl_down(p, 1, 16);
    if (lane == 0) out[l] = p;
}

// ---------------------------------------------------------------------------
extern "C" void kernel_launch(void* const* d_in, const int* in_sizes, int n_in,
                              void* d_out, int out_size, void* d_ws, size_t ws_size,
                              hipStream_t stream) {
    const float* x     = (const float*)d_in[0];
    const int*   ei    = (const int*)d_in[1];   // [2, 800000]: row0 src, row1 dst
    const int*   eli   = (const int*)d_in[2];   // [2, 200000]
    const float* W1l   = (const float*)d_in[3];
    const float* W1r   = (const float*)d_in[4];
    const float* b1    = (const float*)d_in[5];
    const float* gamma = (const float*)d_in[6];
    const float* beta  = (const float*)d_in[7];
    const float* W2l   = (const float*)d_in[8];
    const float* W2r   = (const float*)d_in[9];
    const float* b2    = (const float*)d_in[10];
    float* out = (float*)d_out;

    const int* src  = ei;
    const int* dstv = ei + N_EDGES;

    // workspace layout (ints first, then floats; all 16B-aligned)
    int* ideg = (int*)d_ws;              // 50048
    int* ioff = ideg + 50048;            // 50056 (need 50001)
    int* icur = ioff + 50056;            // 50048
    int* icsr = icur + 50048;            // 800000
    float* bufA = (float*)(icsr + 800000);  // 6.4M : y1 | later t2l(3.2M)+t2r(3.2M)
    float* bufB = bufA + 6400000;           // 6.4M : h  | later z(3.2M)
    float* sums = bufB + 6400000;           // 256
    float* ss   = sums + 256;               // 256

    float* y1  = bufA;
    float* h   = bufB;
    float* t2l = bufA;
    float* t2r = bufA + 3200000;
    float* z   = bufB;

    hipMemsetAsync(ideg, 0, 50048 * sizeof(int), stream);
    hipMemsetAsync(sums, 0, 256 * sizeof(float), stream);

    // ---- CSR build ----
    hist_kernel<<<(N_EDGES + 255) / 256, 256, 0, stream>>>(dstv, ideg);
    scan_kernel<<<1, 256, 0, stream>>>(ideg, ioff, icur);
    scatter_kernel<<<(N_EDGES + 255) / 256, 256, 0, stream>>>(src, dstv, icur, icsr);

    // ---- conv1: y1 = x@W1l, h = x@W1r + b1, then h += mean-gather(y1) ----
    gemm1_dual<<<(N_NODES + 15) / 16, 256, 0, stream>>>(x, W1l, W1r, b1, y1, h);
    agg_mean_add_128<<<(N_NODES + 3) / 4, 256, 0, stream>>>(ioff, icsr, y1, h);

    // ---- batchnorm stats (apply is fused into gemm2 staging) ----
    bn_stats_kernel<<<500, 256, 0, stream>>>(h, sums);
    bn_finalize_kernel<<<1, 128, 0, stream>>>(sums, gamma, beta, ss);

    // ---- conv2: t2l = relu(bn(h))@W2l, t2r = relu(bn(h))@W2r + b2 ----
    gemm2_dual<<<(N_NODES + 15) / 16, 256, 0, stream>>>(h, ss, W2l, W2r, b2, t2l, t2r);
    agg_mean_add_64<<<(N_NODES + 3) / 4, 256, 0, stream>>>(ioff, icsr, t2l, t2r, z);

    // ---- edge dot readout ----
    edge_dot_kernel<<<((long long)N_LABEL * 16 + 255) / 256, 256, 0, stream>>>(eli, z, out);
}

// Round 3
// 518.937 us; speedup vs baseline: 5.7504x; 1.9214x over previous
//
#include <hip/hip_runtime.h>

constexpr int N_NODES = 50000;
constexpr int IN_C    = 128;
constexpr int HID_C   = 128;
constexpr int OUT_C   = 64;
constexpr int N_EDGES = 800000;
constexpr int N_LABEL = 200000;
constexpr float BN_EPS = 1e-5f;

// ---------------------------------------------------------------------------
// CSR build step 1: histogram of dst
__global__ void hist_kernel(const int* __restrict__ dst, int* __restrict__ deg) {
    int e = blockIdx.x * blockDim.x + threadIdx.x;
    if (e < N_EDGES) atomicAdd(&deg[dst[e]], 1);
}

// CSR build step 2: exclusive scan of deg -> off, copy to cursor. Single block.
__global__ void scan_kernel(const int* __restrict__ deg, int* __restrict__ off,
                            int* __restrict__ cursor) {
    __shared__ int tsum[256];
    int tid = threadIdx.x;
    constexpr int CH = (N_NODES + 255) / 256;   // 196
    int beg = tid * CH;
    int end = min(beg + CH, N_NODES);
    int s = 0;
    for (int i = beg; i < end; ++i) s += deg[i];
    tsum[tid] = s;
    __syncthreads();
    // Hillis-Steele inclusive scan over 256 thread sums
    for (int o = 1; o < 256; o <<= 1) {
        int v = tsum[tid];
        int add = (tid >= o) ? tsum[tid - o] : 0;
        __syncthreads();
        tsum[tid] = v + add;
        __syncthreads();
    }
    int run = (tid == 0) ? 0 : tsum[tid - 1];
    for (int i = beg; i < end; ++i) {
        off[i] = run;
        cursor[i] = run;
        run += deg[i];
    }
    if (tid == 255) off[N_NODES] = run;   // == N_EDGES
}

// CSR build step 3: scatter src ids into csr order
__global__ void scatter_kernel(const int* __restrict__ src, const int* __restrict__ dst,
                               int* __restrict__ cursor, int* __restrict__ csr_src) {
    int e = blockIdx.x * blockDim.x + threadIdx.x;
    if (e < N_EDGES) {
        int pos = atomicAdd(&cursor[dst[e]], 1);
        csr_src[pos] = src[e];
    }
}

// ---------------------------------------------------------------------------
// GEMM1 dual: y1 = x @ W1l ; h = x @ W1r + b1     (x:[N,128], W:[128,128])
// block: 16 rows staged in LDS; 256 threads; col=tid&127, 8 rows/thread
// #pragma unroll 2 on the k-loop: bounded unroll so weight loads don't get
// fully hoisted into registers (round-2 gemm2 spilled at VGPR=256).
__global__ __launch_bounds__(256) void gemm1_dual(
    const float* __restrict__ x, const float* __restrict__ Wl,
    const float* __restrict__ Wr, const float* __restrict__ bias,
    float* __restrict__ y1, float* __restrict__ h) {
    __shared__ float sx[16][128];
    int row0 = blockIdx.x * 16;
    for (int i = threadIdx.x; i < 16 * 128; i += 256) {
        int r = i >> 7, c = i & 127;
        int row = row0 + r;
        sx[r][c] = (row < N_NODES) ? x[(long long)row * 128 + c] : 0.f;
    }
    __syncthreads();
    int col = threadIdx.x & 127;
    int rb  = (threadIdx.x >> 7) * 8;    // 0 or 8
    float bb = bias[col];
    float accL[8] = {0.f, 0.f, 0.f, 0.f, 0.f, 0.f, 0.f, 0.f};
    float accR[8];
    #pragma unroll
    for (int r = 0; r < 8; ++r) accR[r] = bb;
    #pragma unroll 2
    for (int k4 = 0; k4 < 128; k4 += 4) {
        float4 xv[8];
        #pragma unroll
        for (int r = 0; r < 8; ++r)
            xv[r] = *reinterpret_cast<const float4*>(&sx[rb + r][k4]);
        #pragma unroll
        for (int kk = 0; kk < 4; ++kk) {
            float wl = Wl[(k4 + kk) * 128 + col];
            float wr = Wr[(k4 + kk) * 128 + col];
            #pragma unroll
            for (int r = 0; r < 8; ++r) {
                float xs = (&xv[r].x)[kk];
                accL[r] += xs * wl;
                accR[r] += xs * wr;
            }
        }
    }
    #pragma unroll
    for (int r = 0; r < 8; ++r) {
        int row = row0 + rb + r;
        if (row < N_NODES) {
            y1[(long long)row * 128 + col] = accL[r];
            h [(long long)row * 128 + col] = accR[r];
        }
    }
}

// ---------------------------------------------------------------------------
// conv1 aggregate: h[n] += mean_{s in N(n)} y1[s]   (128 ch, wave per node)
__global__ __launch_bounds__(256) void agg_mean_add_128(
    const int* __restrict__ off, const int* __restrict__ csr_src,
    const float* __restrict__ y, float* __restrict__ h) {
    int node = blockIdx.x * 4 + (threadIdx.x >> 6);
    if (node >= N_NODES) return;
    int lane = threadIdx.x & 63;
    int beg = off[node], end = off[node + 1];
    float ax0 = 0.f, ay0 = 0.f, ax1 = 0.f, ay1 = 0.f;
    int i = beg;
    for (; i + 1 < end; i += 2) {
        int s0 = csr_src[i];
        int s1 = csr_src[i + 1];
        float2 v0 = *reinterpret_cast<const float2*>(y + (long long)s0 * 128 + lane * 2);
        float2 v1 = *reinterpret_cast<const float2*>(y + (long long)s1 * 128 + lane * 2);
        ax0 += v0.x; ay0 += v0.y;
        ax1 += v1.x; ay1 += v1.y;
    }
    if (i < end) {
        int s0 = csr_src[i];
        float2 v0 = *reinterpret_cast<const float2*>(y + (long long)s0 * 128 + lane * 2);
        ax0 += v0.x; ay0 += v0.y;
    }
    float inv = (end > beg) ? 1.0f / (float)(end - beg) : 0.f;
    float2* hp = reinterpret_cast<float2*>(h + (long long)node * 128 + lane * 2);
    float2 hv = *hp;
    hv.x += (ax0 + ax1) * inv;
    hv.y += (ay0 + ay1) * inv;
    *hp = hv;
}

// ---------------------------------------------------------------------------
// BN stats: sums[c] = sum_r h[r][c], sums[128+c] = sum_r h[r][c]^2
__global__ void bn_stats_kernel(const float* __restrict__ h, float* __restrict__ sums) {
    int c = threadIdx.x & 127;
    int r0 = blockIdx.x * 2 + (threadIdx.x >> 7);
    int stride = gridDim.x * 2;
    float s = 0.f, sq = 0.f;
    for (int r = r0; r < N_NODES; r += stride) {
        float v = h[(long long)r * 128 + c];
        s += v;
        sq += v * v;
    }
    atomicAdd(&sums[c], s);
    atomicAdd(&sums[128 + c], sq);
}

// scale/shift: ss[c] = gamma*rsqrt(var+eps); ss[128+c] = beta - mu*scale
__global__ void bn_finalize_kernel(const float* __restrict__ sums,
                                   const float* __restrict__ gamma,
                                   const float* __restrict__ beta,
                                   float* __restrict__ ss) {
    int c = threadIdx.x;
    float mu  = sums[c] * (1.0f / N_NODES);
    float var = sums[128 + c] * (1.0f / N_NODES) - mu * mu;
    float sc = gamma[c] * rsqrtf(var + BN_EPS);
    ss[c] = sc;
    ss[128 + c] = beta[c] - mu * sc;
}

// ---------------------------------------------------------------------------
// GEMM2 dual with fused BN+ReLU on the staged load:
//   hb = relu(h*scale + shift);  t2l = hb @ W2l ; t2r = hb @ W2r + b2
// block: 32 rows; 256 threads; col=tid&63, 8 rows/thread (4 row groups)
__global__ __launch_bounds__(256) void gemm2_dual(
    const float* __restrict__ h, const float* __restrict__ ss,
    const float* __restrict__ Wl, const float* __restrict__ Wr,
    const float* __restrict__ bias, float* __restrict__ t2l, float* __restrict__ t2r) {
    __shared__ float sx[32][128];
    int row0 = blockIdx.x * 32;
    for (int i = threadIdx.x; i < 32 * 128; i += 256) {
        int r = i >> 7, c = i & 127;
        int row = row0 + r;
        float v = (row < N_NODES) ? h[(long long)row * 128 + c] : 0.f;
        sx[r][c] = fmaxf(v * ss[c] + ss[128 + c], 0.f);
    }
    __syncthreads();
    int col = threadIdx.x & 63;
    int rb  = (threadIdx.x >> 6) * 8;    // 0,8,16,24
    float bb = bias[col];
    float accL[8] = {0.f, 0.f, 0.f, 0.f, 0.f, 0.f, 0.f, 0.f};
    float accR[8];
    #pragma unroll
    for (int r = 0; r < 8; ++r) accR[r] = bb;
    #pragma unroll 2
    for (int k4 = 0; k4 < 128; k4 += 4) {
        float4 xv[8];
        #pragma unroll
        for (int r = 0; r < 8; ++r)
            xv[r] = *reinterpret_cast<const float4*>(&sx[rb + r][k4]);
        #pragma unroll
        for (int kk = 0; kk < 4; ++kk) {
            float wl = Wl[(k4 + kk) * 64 + col];
            float wr = Wr[(k4 + kk) * 64 + col];
            #pragma unroll
            for (int r = 0; r < 8; ++r) {
                float xs = (&xv[r].x)[kk];
                accL[r] += xs * wl;
                accR[r] += xs * wr;
            }
        }
    }
    #pragma unroll
    for (int r = 0; r < 8; ++r) {
        int row = row0 + rb + r;
        if (row < N_NODES) {
            t2l[(long long)row * 64 + col] = accL[r];
            t2r[(long long)row * 64 + col] = accR[r];
        }
    }
}

// ---------------------------------------------------------------------------
// conv2 aggregate: z[n] = mean_{s in N(n)} t2l[s] + t2r[n]   (64 ch, wave/node)
__global__ __launch_bounds__(256) void agg_mean_add_64(
    const int* __restrict__ off, const int* __restrict__ csr_src,
    const float* __restrict__ t2l, const float* __restrict__ t2r,
    float* __restrict__ z) {
    int node = blockIdx.x * 4 + (threadIdx.x >> 6);
    if (node >= N_NODES) return;
    int lane = threadIdx.x & 63;
    int beg = off[node], end = off[node + 1];
    float a0 = 0.f, a1 = 0.f;
    int i = beg;
    for (; i + 1 < end; i += 2) {
        int s0 = csr_src[i];
        int s1 = csr_src[i + 1];
        a0 += t2l[(long long)s0 * 64 + lane];
        a1 += t2l[(long long)s1 * 64 + lane];
    }
    if (i < end) a0 += t2l[(long long)csr_src[i] * 64 + lane];
    float inv = (end > beg) ? 1.0f / (float)(end - beg) : 0.f;
    z[(long long)node * 64 + lane] = t2r[(long long)node * 64 + lane] + (a0 + a1) * inv;
}

// ---------------------------------------------------------------------------
// out[l] = dot(z[src_l], z[dst_l]) over 64 channels; 16 lanes per label
__global__ void edge_dot_kernel(const int* __restrict__ eli, const float* __restrict__ z,
                                float* __restrict__ out) {
    long long gid = (long long)blockIdx.x * blockDim.x + threadIdx.x;
    int l = (int)(gid >> 4);
    int lane = (int)(gid & 15);
    if (l >= N_LABEL) return;
    int s = eli[l];
    int d = eli[N_LABEL + l];
    const float4 a = *reinterpret_cast<const float4*>(z + (long long)s * 64 + lane * 4);
    const float4 b = *reinterpret_cast<const float4*>(z + (long long)d * 64 + lane * 4);
    float p = a.x * b.x + a.y * b.y + a.z * b.z + a.w * b.w;
    p += __shfl_down(p, 8, 16);
    p += __shfl_down(p, 4, 16);
    p += __shfl_down(p, 2, 16);
    p += __shfl_down(p, 1, 16);
    if (lane == 0) out[l] = p;
}

// ---------------------------------------------------------------------------
extern "C" void kernel_launch(void* const* d_in, const int* in_sizes, int n_in,
                              void* d_out, int out_size, void* d_ws, size_t ws_size,
                              hipStream_t stream) {
    const float* x     = (const float*)d_in[0];
    const int*   ei    = (const int*)d_in[1];   // [2, 800000]: row0 src, row1 dst
    const int*   eli   = (const int*)d_in[2];   // [2, 200000]
    const float* W1l   = (const float*)d_in[3];
    const float* W1r   = (const float*)d_in[4];
    const float* b1    = (const float*)d_in[5];
    const float* gamma = (const float*)d_in[6];
    const float* beta  = (const float*)d_in[7];
    const float* W2l   = (const float*)d_in[8];
    const float* W2r   = (const float*)d_in[9];
    const float* b2    = (const float*)d_in[10];
    float* out = (float*)d_out;

    const int* src  = ei;
    const int* dstv = ei + N_EDGES;

    // workspace layout (ints first, then floats; all 16B-aligned)
    int* ideg = (int*)d_ws;              // 50048
    int* ioff = ideg + 50048;            // 50056 (need 50001)
    int* icur = ioff + 50056;            // 50048
    int* icsr = icur + 50048;            // 800000
    float* bufA = (float*)(icsr + 800000);  // 6.4M : y1 | later t2l(3.2M)+t2r(3.2M)
    float* bufB = bufA + 6400000;           // 6.4M : h  | later z(3.2M)
    float* sums = bufB + 6400000;           // 256
    float* ss   = sums + 256;               // 256

    float* y1  = bufA;
    float* h   = bufB;
    float* t2l = bufA;
    float* t2r = bufA + 3200000;
    float* z   = bufB;

    hipMemsetAsync(ideg, 0, 50048 * sizeof(int), stream);
    hipMemsetAsync(sums, 0, 256 * sizeof(float), stream);

    // ---- CSR build ----
    hist_kernel<<<(N_EDGES + 255) / 256, 256, 0, stream>>>(dstv, ideg);
    scan_kernel<<<1, 256, 0, stream>>>(ideg, ioff, icur);
    scatter_kernel<<<(N_EDGES + 255) / 256, 256, 0, stream>>>(src, dstv, icur, icsr);

    // ---- conv1: y1 = x@W1l, h = x@W1r + b1, then h += mean-gather(y1) ----
    gemm1_dual<<<(N_NODES + 15) / 16, 256, 0, stream>>>(x, W1l, W1r, b1, y1, h);
    agg_mean_add_128<<<(N_NODES + 3) / 4, 256, 0, stream>>>(ioff, icsr, y1, h);

    // ---- batchnorm stats (apply is fused into gemm2 staging) ----
    bn_stats_kernel<<<500, 256, 0, stream>>>(h, sums);
    bn_finalize_kernel<<<1, 128, 0, stream>>>(sums, gamma, beta, ss);

    // ---- conv2: t2l = relu(bn(h))@W2l, t2r = relu(bn(h))@W2r + b2 ----
    gemm2_dual<<<(N_NODES + 31) / 32, 256, 0, stream>>>(h, ss, W2l, W2r, b2, t2l, t2r);
    agg_mean_add_64<<<(N_NODES + 3) / 4, 256, 0, stream>>>(ioff, icsr, t2l, t2r, z);

    // ---- edge dot readout ----
    edge_dot_kernel<<<((long long)N_LABEL * 16 + 255) / 256, 256, 0, stream>>>(eli, z, out);
}

// Round 4
// 388.946 us; speedup vs baseline: 7.6722x; 1.3342x over previous
//
#include <hip/hip_runtime.h>

constexpr int N_NODES = 50000;
constexpr int IN_C    = 128;
constexpr int HID_C   = 128;
constexpr int OUT_C   = 64;
constexpr int N_EDGES = 800000;
constexpr int N_LABEL = 200000;
constexpr float BN_EPS = 1e-5f;
constexpr int NCHUNK  = (N_NODES + 256) / 256 + 1;   // 196 chunks cover 50176 >= 50001

// ---------------------------------------------------------------------------
// CSR build step 1: histogram of dst
__global__ void hist_kernel(const int* __restrict__ dst, int* __restrict__ deg) {
    int e = blockIdx.x * blockDim.x + threadIdx.x;
    if (e < N_EDGES) atomicAdd(&deg[dst[e]], 1);
}

// CSR build step 2a: per-chunk sums (deg is zero-padded past N_NODES)
__global__ void chunk_sum_kernel(const int* __restrict__ deg, int* __restrict__ bsum) {
    int i = blockIdx.x * 256 + threadIdx.x;
    int v = deg[i];
    #pragma unroll
    for (int o = 32; o > 0; o >>= 1) v += __shfl_down(v, o, 64);
    __shared__ int ws[4];
    if ((threadIdx.x & 63) == 0) ws[threadIdx.x >> 6] = v;
    __syncthreads();
    if (threadIdx.x == 0) bsum[blockIdx.x] = ws[0] + ws[1] + ws[2] + ws[3];
}

// CSR build step 2b: exclusive scan of the 196 chunk sums (single tiny block)
__global__ void scan_bsum_kernel(const int* __restrict__ bsum, int* __restrict__ boff) {
    __shared__ int t[256];
    int tid = threadIdx.x;
    t[tid] = (tid < NCHUNK) ? bsum[tid] : 0;
    __syncthreads();
    for (int o = 1; o < 256; o <<= 1) {
        int v = t[tid];
        int add = (tid >= o) ? t[tid - o] : 0;
        __syncthreads();
        t[tid] = v + add;
        __syncthreads();
    }
    boff[tid] = (tid == 0) ? 0 : t[tid - 1];
}

// CSR build step 2c: per-chunk exclusive scan + chunk offset -> off, cursor
__global__ void scan_final_kernel(const int* __restrict__ deg, const int* __restrict__ boff,
                                  int* __restrict__ off, int* __restrict__ cursor) {
    __shared__ int t[256];
    int tid = threadIdx.x;
    int i = blockIdx.x * 256 + tid;
    int d = deg[i];
    t[tid] = d;
    __syncthreads();
    for (int o = 1; o < 256; o <<= 1) {
        int v = t[tid];
        int add = (tid >= o) ? t[tid - o] : 0;
        __syncthreads();
        t[tid] = v + add;
        __syncthreads();
    }
    int excl = boff[blockIdx.x] + t[tid] - d;
    if (i <= N_NODES) {
        off[i] = excl;                     // off[N_NODES] == N_EDGES (deg pad = 0)
        if (i < N_NODES) cursor[i] = excl;
    }
}

// CSR build step 3: scatter src ids into csr order
__global__ void scatter_kernel(const int* __restrict__ src, const int* __restrict__ dst,
                               int* __restrict__ cursor, int* __restrict__ csr_src) {
    int e = blockIdx.x * blockDim.x + threadIdx.x;
    if (e < N_EDGES) {
        int pos = atomicAdd(&cursor[dst[e]], 1);
        csr_src[pos] = src[e];
    }
}

// ---------------------------------------------------------------------------
// GEMM1 dual: y1 = x @ W1l ; h = x @ W1r + b1     (x:[N,128], W:[128,128])
// block: 16 rows staged in LDS; 256 threads; col=tid&127, 8 rows/thread
// #pragma unroll 2: bounded unroll so weight loads aren't fully hoisted (r2 spill)
__global__ __launch_bounds__(256) void gemm1_dual(
    const float* __restrict__ x, const float* __restrict__ Wl,
    const float* __restrict__ Wr, const float* __restrict__ bias,
    float* __restrict__ y1, float* __restrict__ h) {
    __shared__ float sx[16][128];
    int row0 = blockIdx.x * 16;
    for (int i = threadIdx.x; i < 16 * 128; i += 256) {
        int r = i >> 7, c = i & 127;
        int row = row0 + r;
        sx[r][c] = (row < N_NODES) ? x[(long long)row * 128 + c] : 0.f;
    }
    __syncthreads();
    int col = threadIdx.x & 127;
    int rb  = (threadIdx.x >> 7) * 8;    // 0 or 8
    float bb = bias[col];
    float accL[8] = {0.f, 0.f, 0.f, 0.f, 0.f, 0.f, 0.f, 0.f};
    float accR[8];
    #pragma unroll
    for (int r = 0; r < 8; ++r) accR[r] = bb;
    #pragma unroll 2
    for (int k4 = 0; k4 < 128; k4 += 4) {
        float4 xv[8];
        #pragma unroll
        for (int r = 0; r < 8; ++r)
            xv[r] = *reinterpret_cast<const float4*>(&sx[rb + r][k4]);
        #pragma unroll
        for (int kk = 0; kk < 4; ++kk) {
            float wl = Wl[(k4 + kk) * 128 + col];
            float wr = Wr[(k4 + kk) * 128 + col];
            #pragma unroll
            for (int r = 0; r < 8; ++r) {
                float xs = (&xv[r].x)[kk];
                accL[r] += xs * wl;
                accR[r] += xs * wr;
            }
        }
    }
    #pragma unroll
    for (int r = 0; r < 8; ++r) {
        int row = row0 + rb + r;
        if (row < N_NODES) {
            y1[(long long)row * 128 + col] = accL[r];
            h [(long long)row * 128 + col] = accR[r];
        }
    }
}

// ---------------------------------------------------------------------------
// conv1 aggregate: h[n] += mean_{s in N(n)} y1[s]   (128 ch, wave per node)
// 4-edge unroll for memory-level parallelism (latency-bound random rows)
__global__ __launch_bounds__(256) void agg_mean_add_128(
    const int* __restrict__ off, const int* __restrict__ csr_src,
    const float* __restrict__ y, float* __restrict__ h) {
    int node = blockIdx.x * 4 + (threadIdx.x >> 6);
    if (node >= N_NODES) return;
    int lane = threadIdx.x & 63;
    int beg = off[node], end = off[node + 1];
    float ax = 0.f, ay = 0.f;
    int i = beg;
    for (; i + 3 < end; i += 4) {
        int s0 = csr_src[i];
        int s1 = csr_src[i + 1];
        int s2 = csr_src[i + 2];
        int s3 = csr_src[i + 3];
        float2 v0 = *reinterpret_cast<const float2*>(y + (long long)s0 * 128 + lane * 2);
        float2 v1 = *reinterpret_cast<const float2*>(y + (long long)s1 * 128 + lane * 2);
        float2 v2 = *reinterpret_cast<const float2*>(y + (long long)s2 * 128 + lane * 2);
        float2 v3 = *reinterpret_cast<const float2*>(y + (long long)s3 * 128 + lane * 2);
        ax += v0.x + v1.x + v2.x + v3.x;
        ay += v0.y + v1.y + v2.y + v3.y;
    }
    for (; i < end; ++i) {
        int s0 = csr_src[i];
        float2 v0 = *reinterpret_cast<const float2*>(y + (long long)s0 * 128 + lane * 2);
        ax += v0.x; ay += v0.y;
    }
    float inv = (end > beg) ? 1.0f / (float)(end - beg) : 0.f;
    float2* hp = reinterpret_cast<float2*>(h + (long long)node * 128 + lane * 2);
    float2 hv = *hp;
    hv.x += ax * inv;
    hv.y += ay * inv;
    *hp = hv;
}

// ---------------------------------------------------------------------------
// BN stats: sums[c] = sum_r h[r][c], sums[128+c] = sum_r h[r][c]^2
__global__ void bn_stats_kernel(const float* __restrict__ h, float* __restrict__ sums) {
    int c = threadIdx.x & 127;
    int r0 = blockIdx.x * 2 + (threadIdx.x >> 7);
    int stride = gridDim.x * 2;
    float s = 0.f, sq = 0.f;
    for (int r = r0; r < N_NODES; r += stride) {
        float v = h[(long long)r * 128 + c];
        s += v;
        sq += v * v;
    }
    atomicAdd(&sums[c], s);
    atomicAdd(&sums[128 + c], sq);
}

// scale/shift: ss[c] = gamma*rsqrt(var+eps); ss[128+c] = beta - mu*scale
__global__ void bn_finalize_kernel(const float* __restrict__ sums,
                                   const float* __restrict__ gamma,
                                   const float* __restrict__ beta,
                                   float* __restrict__ ss) {
    int c = threadIdx.x;
    float mu  = sums[c] * (1.0f / N_NODES);
    float var = sums[128 + c] * (1.0f / N_NODES) - mu * mu;
    float sc = gamma[c] * rsqrtf(var + BN_EPS);
    ss[c] = sc;
    ss[128 + c] = beta[c] - mu * sc;
}

// ---------------------------------------------------------------------------
// GEMM2 dual with fused BN+ReLU on the staged load:
//   hb = relu(h*scale + shift);  t2l = hb @ W2l ; t2r = hb @ W2r + b2
// block: 32 rows; 256 threads; col=tid&63, 8 rows/thread (4 row groups)
__global__ __launch_bounds__(256) void gemm2_dual(
    const float* __restrict__ h, const float* __restrict__ ss,
    const float* __restrict__ Wl, const float* __restrict__ Wr,
    const float* __restrict__ bias, float* __restrict__ t2l, float* __restrict__ t2r) {
    __shared__ float sx[32][128];
    int row0 = blockIdx.x * 32;
    for (int i = threadIdx.x; i < 32 * 128; i += 256) {
        int r = i >> 7, c = i & 127;
        int row = row0 + r;
        float v = (row < N_NODES) ? h[(long long)row * 128 + c] : 0.f;
        sx[r][c] = fmaxf(v * ss[c] + ss[128 + c], 0.f);
    }
    __syncthreads();
    int col = threadIdx.x & 63;
    int rb  = (threadIdx.x >> 6) * 8;    // 0,8,16,24
    float bb = bias[col];
    float accL[8] = {0.f, 0.f, 0.f, 0.f, 0.f, 0.f, 0.f, 0.f};
    float accR[8];
    #pragma unroll
    for (int r = 0; r < 8; ++r) accR[r] = bb;
    #pragma unroll 2
    for (int k4 = 0; k4 < 128; k4 += 4) {
        float4 xv[8];
        #pragma unroll
        for (int r = 0; r < 8; ++r)
            xv[r] = *reinterpret_cast<const float4*>(&sx[rb + r][k4]);
        #pragma unroll
        for (int kk = 0; kk < 4; ++kk) {
            float wl = Wl[(k4 + kk) * 64 + col];
            float wr = Wr[(k4 + kk) * 64 + col];
            #pragma unroll
            for (int r = 0; r < 8; ++r) {
                float xs = (&xv[r].x)[kk];
                accL[r] += xs * wl;
                accR[r] += xs * wr;
            }
        }
    }
    #pragma unroll
    for (int r = 0; r < 8; ++r) {
        int row = row0 + rb + r;
        if (row < N_NODES) {
            t2l[(long long)row * 64 + col] = accL[r];
            t2r[(long long)row * 64 + col] = accR[r];
        }
    }
}

// ---------------------------------------------------------------------------
// conv2 aggregate: z[n] = mean_{s in N(n)} t2l[s] + t2r[n]   (64 ch, wave/node)
__global__ __launch_bounds__(256) void agg_mean_add_64(
    const int* __restrict__ off, const int* __restrict__ csr_src,
    const float* __restrict__ t2l, const float* __restrict__ t2r,
    float* __restrict__ z) {
    int node = blockIdx.x * 4 + (threadIdx.x >> 6);
    if (node >= N_NODES) return;
    int lane = threadIdx.x & 63;
    int beg = off[node], end = off[node + 1];
    float a = 0.f;
    int i = beg;
    for (; i + 3 < end; i += 4) {
        int s0 = csr_src[i];
        int s1 = csr_src[i + 1];
        int s2 = csr_src[i + 2];
        int s3 = csr_src[i + 3];
        a += t2l[(long long)s0 * 64 + lane] + t2l[(long long)s1 * 64 + lane]
           + t2l[(long long)s2 * 64 + lane] + t2l[(long long)s3 * 64 + lane];
    }
    for (; i < end; ++i) a += t2l[(long long)csr_src[i] * 64 + lane];
    float inv = (end > beg) ? 1.0f / (float)(end - beg) : 0.f;
    z[(long long)node * 64 + lane] = t2r[(long long)node * 64 + lane] + a * inv;
}

// ---------------------------------------------------------------------------
// out[l] = dot(z[src_l], z[dst_l]) over 64 channels; 16 lanes per label
__global__ void edge_dot_kernel(const int* __restrict__ eli, const float* __restrict__ z,
                                float* __restrict__ out) {
    long long gid = (long long)blockIdx.x * blockDim.x + threadIdx.x;
    int l = (int)(gid >> 4);
    int lane = (int)(gid & 15);
    if (l >= N_LABEL) return;
    int s = eli[l];
    int d = eli[N_LABEL + l];
    const float4 a = *reinterpret_cast<const float4*>(z + (long long)s * 64 + lane * 4);
    const float4 b = *reinterpret_cast<const float4*>(z + (long long)d * 64 + lane * 4);
    float p = a.x * b.x + a.y * b.y + a.z * b.z + a.w * b.w;
    p += __shfl_down(p, 8, 16);
    p += __shfl_down(p, 4, 16);
    p += __shfl_down(p, 2, 16);
    p += __shfl_down(p, 1, 16);
    if (lane == 0) out[l] = p;
}

// ---------------------------------------------------------------------------
extern "C" void kernel_launch(void* const* d_in, const int* in_sizes, int n_in,
                              void* d_out, int out_size, void* d_ws, size_t ws_size,
                              hipStream_t stream) {
    const float* x     = (const float*)d_in[0];
    const int*   ei    = (const int*)d_in[1];   // [2, 800000]: row0 src, row1 dst
    const int*   eli   = (const int*)d_in[2];   // [2, 200000]
    const float* W1l   = (const float*)d_in[3];
    const float* W1r   = (const float*)d_in[4];
    const float* b1    = (const float*)d_in[5];
    const float* gamma = (const float*)d_in[6];
    const float* beta  = (const float*)d_in[7];
    const float* W2l   = (const float*)d_in[8];
    const float* W2r   = (const float*)d_in[9];
    const float* b2    = (const float*)d_in[10];
    float* out = (float*)d_out;

    const int* src  = ei;
    const int* dstv = ei + N_EDGES;

    // workspace layout (ints first, then floats; all 16B-aligned)
    // deg padded/zeroed to 50432 >= NCHUNK*256 = 50176
    int* ideg = (int*)d_ws;              // 50432
    int* ioff = ideg + 50432;            // 50056 (need 50001)
    int* icur = ioff + 50056;            // 50048
    int* ibsum = icur + 50048;           // 256
    int* iboff = ibsum + 256;            // 256
    int* icsr = iboff + 256;             // 800000
    float* bufA = (float*)(icsr + 800000);  // 6.4M : y1 | later t2l(3.2M)+t2r(3.2M)
    float* bufB = bufA + 6400000;           // 6.4M : h  | later z(3.2M)
    float* sums = bufB + 6400000;           // 256
    float* ss   = sums + 256;               // 256

    float* y1  = bufA;
    float* h   = bufB;
    float* t2l = bufA;
    float* t2r = bufA + 3200000;
    float* z   = bufB;

    hipMemsetAsync(ideg, 0, 50432 * sizeof(int), stream);
    hipMemsetAsync(sums, 0, 256 * sizeof(float), stream);

    // ---- CSR build ----
    hist_kernel<<<(N_EDGES + 255) / 256, 256, 0, stream>>>(dstv, ideg);
    chunk_sum_kernel<<<NCHUNK, 256, 0, stream>>>(ideg, ibsum);
    scan_bsum_kernel<<<1, 256, 0, stream>>>(ibsum, iboff);
    scan_final_kernel<<<NCHUNK, 256, 0, stream>>>(ideg, iboff, ioff, icur);
    scatter_kernel<<<(N_EDGES + 255) / 256, 256, 0, stream>>>(src, dstv, icur, icsr);

    // ---- conv1: y1 = x@W1l, h = x@W1r + b1, then h += mean-gather(y1) ----
    gemm1_dual<<<(N_NODES + 15) / 16, 256, 0, stream>>>(x, W1l, W1r, b1, y1, h);
    agg_mean_add_128<<<(N_NODES + 3) / 4, 256, 0, stream>>>(ioff, icsr, y1, h);

    // ---- batchnorm stats (apply is fused into gemm2 staging) ----
    bn_stats_kernel<<<500, 256, 0, stream>>>(h, sums);
    bn_finalize_kernel<<<1, 128, 0, stream>>>(sums, gamma, beta, ss);

    // ---- conv2: t2l = relu(bn(h))@W2l, t2r = relu(bn(h))@W2r + b2 ----
    gemm2_dual<<<(N_NODES + 31) / 32, 256, 0, stream>>>(h, ss, W2l, W2r, b2, t2l, t2r);
    agg_mean_add_64<<<(N_NODES + 3) / 4, 256, 0, stream>>>(ioff, icsr, t2l, t2r, z);

    // ---- edge dot readout ----
    edge_dot_kernel<<<((long long)N_LABEL * 16 + 255) / 256, 256, 0, stream>>>(eli, z, out);
}

// Round 5
// 355.198 us; speedup vs baseline: 8.4012x; 1.0950x over previous
//
#include <hip/hip_runtime.h>
#include <hip/hip_bf16.h>

constexpr int N_NODES = 50000;
constexpr int IN_C    = 128;
constexpr int HID_C   = 128;
constexpr int OUT_C   = 64;
constexpr int N_EDGES = 800000;
constexpr int N_LABEL = 200000;
constexpr float BN_EPS = 1e-5f;
constexpr int NCHUNK  = (N_NODES + 256) / 256 + 1;   // 196 chunks cover 50176 >= 50001

// ---- bf16 helpers (plain ushort storage) ----------------------------------
__device__ __forceinline__ float bf_lo(unsigned v) {
    union { unsigned u; float f; } t; t.u = v << 16; return t.f;
}
__device__ __forceinline__ float bf_hi(unsigned v) {
    union { unsigned u; float f; } t; t.u = v & 0xffff0000u; return t.f;
}
__device__ __forceinline__ float bf1(unsigned short u) {
    union { unsigned u; float f; } t; t.u = ((unsigned)u) << 16; return t.f;
}
__device__ __forceinline__ unsigned short f2bf(float f) {
    union { float f; unsigned u; } t; t.f = f;
    unsigned r = t.u + 0x7fffu + ((t.u >> 16) & 1u);   // round-nearest-even
    return (unsigned short)(r >> 16);
}

// ---------------------------------------------------------------------------
// CSR build step 1: histogram of dst
__global__ void hist_kernel(const int* __restrict__ dst, int* __restrict__ deg) {
    int e = blockIdx.x * blockDim.x + threadIdx.x;
    if (e < N_EDGES) atomicAdd(&deg[dst[e]], 1);
}

// CSR build step 2a: per-chunk sums (deg is zero-padded past N_NODES)
__global__ void chunk_sum_kernel(const int* __restrict__ deg, int* __restrict__ bsum) {
    int i = blockIdx.x * 256 + threadIdx.x;
    int v = deg[i];
    #pragma unroll
    for (int o = 32; o > 0; o >>= 1) v += __shfl_down(v, o, 64);
    __shared__ int ws[4];
    if ((threadIdx.x & 63) == 0) ws[threadIdx.x >> 6] = v;
    __syncthreads();
    if (threadIdx.x == 0) bsum[blockIdx.x] = ws[0] + ws[1] + ws[2] + ws[3];
}

// CSR build step 2b: exclusive scan of the chunk sums (single tiny block)
__global__ void scan_bsum_kernel(const int* __restrict__ bsum, int* __restrict__ boff) {
    __shared__ int t[256];
    int tid = threadIdx.x;
    t[tid] = (tid < NCHUNK) ? bsum[tid] : 0;
    __syncthreads();
    for (int o = 1; o < 256; o <<= 1) {
        int v = t[tid];
        int add = (tid >= o) ? t[tid - o] : 0;
        __syncthreads();
        t[tid] = v + add;
        __syncthreads();
    }
    boff[tid] = (tid == 0) ? 0 : t[tid - 1];
}

// CSR build step 2c: per-chunk exclusive scan + chunk offset -> off, cursor
__global__ void scan_final_kernel(const int* __restrict__ deg, const int* __restrict__ boff,
                                  int* __restrict__ off, int* __restrict__ cursor) {
    __shared__ int t[256];
    int tid = threadIdx.x;
    int i = blockIdx.x * 256 + tid;
    int d = deg[i];
    t[tid] = d;
    __syncthreads();
    for (int o = 1; o < 256; o <<= 1) {
        int v = t[tid];
        int add = (tid >= o) ? t[tid - o] : 0;
        __syncthreads();
        t[tid] = v + add;
        __syncthreads();
    }
    int excl = boff[blockIdx.x] + t[tid] - d;
    if (i <= N_NODES) {
        off[i] = excl;                     // off[N_NODES] == N_EDGES (deg pad = 0)
        if (i < N_NODES) cursor[i] = excl;
    }
}

// CSR build step 3: scatter src ids into csr order
__global__ void scatter_kernel(const int* __restrict__ src, const int* __restrict__ dst,
                               int* __restrict__ cursor, int* __restrict__ csr_src) {
    int e = blockIdx.x * blockDim.x + threadIdx.x;
    if (e < N_EDGES) {
        int pos = atomicAdd(&cursor[dst[e]], 1);
        csr_src[pos] = src[e];
    }
}

// ---------------------------------------------------------------------------
// GEMM1 dual: y1 = bf16(x @ W1l) ; h = x @ W1r + b1   (x:[N,128], W:[128,128])
// block: 32 rows staged in LDS; 256 threads; col=tid&127, 16 rows/thread
// bounded unroll so weight loads aren't fully hoisted (round-2 spill lesson)
__global__ __launch_bounds__(256) void gemm1_dual(
    const float* __restrict__ x, const float* __restrict__ Wl,
    const float* __restrict__ Wr, const float* __restrict__ bias,
    unsigned short* __restrict__ y1, float* __restrict__ h) {
    __shared__ float sx[32][128];
    int row0 = blockIdx.x * 32;
    for (int i = threadIdx.x; i < 32 * 128; i += 256) {
        int r = i >> 7, c = i & 127;
        int row = row0 + r;
        sx[r][c] = (row < N_NODES) ? x[(long long)row * 128 + c] : 0.f;
    }
    __syncthreads();
    int col = threadIdx.x & 127;
    int rb  = (threadIdx.x >> 7) * 16;   // 0 or 16
    float bb = bias[col];
    float accL[16], accR[16];
    #pragma unroll
    for (int r = 0; r < 16; ++r) { accL[r] = 0.f; accR[r] = bb; }
    #pragma unroll 2
    for (int k4 = 0; k4 < 128; k4 += 4) {
        float4 xv[16];
        #pragma unroll
        for (int r = 0; r < 16; ++r)
            xv[r] = *reinterpret_cast<const float4*>(&sx[rb + r][k4]);
        #pragma unroll
        for (int kk = 0; kk < 4; ++kk) {
            float wl = Wl[(k4 + kk) * 128 + col];
            float wr = Wr[(k4 + kk) * 128 + col];
            #pragma unroll
            for (int r = 0; r < 16; ++r) {
                float xs = (&xv[r].x)[kk];
                accL[r] += xs * wl;
                accR[r] += xs * wr;
            }
        }
    }
    #pragma unroll
    for (int r = 0; r < 16; ++r) {
        int row = row0 + rb + r;
        if (row < N_NODES) {
            y1[(long long)row * 128 + col] = f2bf(accL[r]);
            h [(long long)row * 128 + col] = accR[r];
        }
    }
}

// ---------------------------------------------------------------------------
// conv1 aggregate: h[n] += mean_{s in N(n)} y1[s]  (y1 bf16-packed, 128 ch)
// wave per node; lane reads one uint = 2 bf16 channels; 4-edge unroll for MLP
__global__ __launch_bounds__(256) void agg_mean_add_128(
    const int* __restrict__ off, const int* __restrict__ csr_src,
    const unsigned* __restrict__ ybf, float* __restrict__ h) {
    int node = blockIdx.x * 4 + (threadIdx.x >> 6);
    if (node >= N_NODES) return;
    int lane = threadIdx.x & 63;
    int beg = off[node], end = off[node + 1];
    float ax = 0.f, ay = 0.f;
    int i = beg;
    for (; i + 3 < end; i += 4) {
        int s0 = csr_src[i];
        int s1 = csr_src[i + 1];
        int s2 = csr_src[i + 2];
        int s3 = csr_src[i + 3];
        unsigned v0 = ybf[(long long)s0 * 64 + lane];
        unsigned v1 = ybf[(long long)s1 * 64 + lane];
        unsigned v2 = ybf[(long long)s2 * 64 + lane];
        unsigned v3 = ybf[(long long)s3 * 64 + lane];
        ax += bf_lo(v0) + bf_lo(v1) + bf_lo(v2) + bf_lo(v3);
        ay += bf_hi(v0) + bf_hi(v1) + bf_hi(v2) + bf_hi(v3);
    }
    for (; i < end; ++i) {
        unsigned v0 = ybf[(long long)csr_src[i] * 64 + lane];
        ax += bf_lo(v0); ay += bf_hi(v0);
    }
    float inv = (end > beg) ? 1.0f / (float)(end - beg) : 0.f;
    float2* hp = reinterpret_cast<float2*>(h + (long long)node * 128 + lane * 2);
    float2 hv = *hp;
    hv.x += ax * inv;
    hv.y += ay * inv;
    *hp = hv;
}

// ---------------------------------------------------------------------------
// BN stats: sums[c] = sum_r h[r][c], sums[128+c] = sum_r h[r][c]^2
__global__ void bn_stats_kernel(const float* __restrict__ h, float* __restrict__ sums) {
    int c = threadIdx.x & 127;
    int r0 = blockIdx.x * 2 + (threadIdx.x >> 7);
    int stride = gridDim.x * 2;
    float s = 0.f, sq = 0.f;
    for (int r = r0; r < N_NODES; r += stride) {
        float v = h[(long long)r * 128 + c];
        s += v;
        sq += v * v;
    }
    atomicAdd(&sums[c], s);
    atomicAdd(&sums[128 + c], sq);
}

// scale/shift: ss[c] = gamma*rsqrt(var+eps); ss[128+c] = beta - mu*scale
__global__ void bn_finalize_kernel(const float* __restrict__ sums,
                                   const float* __restrict__ gamma,
                                   const float* __restrict__ beta,
                                   float* __restrict__ ss) {
    int c = threadIdx.x;
    float mu  = sums[c] * (1.0f / N_NODES);
    float var = sums[128 + c] * (1.0f / N_NODES) - mu * mu;
    float sc = gamma[c] * rsqrtf(var + BN_EPS);
    ss[c] = sc;
    ss[128 + c] = beta[c] - mu * sc;
}

// ---------------------------------------------------------------------------
// GEMM2 dual with fused BN+ReLU on the staged load:
//   hb = relu(h*scale + shift);  t2l = bf16(hb @ W2l) ; t2r = hb @ W2r + b2
// block: 32 rows; 256 threads; col=tid&63, 8 rows/thread (4 row groups)
__global__ __launch_bounds__(256) void gemm2_dual(
    const float* __restrict__ h, const float* __restrict__ ss,
    const float* __restrict__ Wl, const float* __restrict__ Wr,
    const float* __restrict__ bias,
    unsigned short* __restrict__ t2l, float* __restrict__ t2r) {
    __shared__ float sx[32][128];
    int row0 = blockIdx.x * 32;
    for (int i = threadIdx.x; i < 32 * 128; i += 256) {
        int r = i >> 7, c = i & 127;
        int row = row0 + r;
        float v = (row < N_NODES) ? h[(long long)row * 128 + c] : 0.f;
        sx[r][c] = fmaxf(v * ss[c] + ss[128 + c], 0.f);
    }
    __syncthreads();
    int col = threadIdx.x & 63;
    int rb  = (threadIdx.x >> 6) * 8;    // 0,8,16,24
    float bb = bias[col];
    float accL[8] = {0.f, 0.f, 0.f, 0.f, 0.f, 0.f, 0.f, 0.f};
    float accR[8];
    #pragma unroll
    for (int r = 0; r < 8; ++r) accR[r] = bb;
    #pragma unroll 2
    for (int k4 = 0; k4 < 128; k4 += 4) {
        float4 xv[8];
        #pragma unroll
        for (int r = 0; r < 8; ++r)
            xv[r] = *reinterpret_cast<const float4*>(&sx[rb + r][k4]);
        #pragma unroll
        for (int kk = 0; kk < 4; ++kk) {
            float wl = Wl[(k4 + kk) * 64 + col];
            float wr = Wr[(k4 + kk) * 64 + col];
            #pragma unroll
            for (int r = 0; r < 8; ++r) {
                float xs = (&xv[r].x)[kk];
                accL[r] += xs * wl;
                accR[r] += xs * wr;
            }
        }
    }
    #pragma unroll
    for (int r = 0; r < 8; ++r) {
        int row = row0 + rb + r;
        if (row < N_NODES) {
            t2l[(long long)row * 64 + col] = f2bf(accL[r]);
            t2r[(long long)row * 64 + col] = accR[r];
        }
    }
}

// ---------------------------------------------------------------------------
// conv2 aggregate: z[n] = bf16( mean_{s in N(n)} t2l[s] + t2r[n] )  (64 ch)
__global__ __launch_bounds__(256) void agg_mean_add_64(
    const int* __restrict__ off, const int* __restrict__ csr_src,
    const unsigned short* __restrict__ t2l, const float* __restrict__ t2r,
    unsigned short* __restrict__ z) {
    int node = blockIdx.x * 4 + (threadIdx.x >> 6);
    if (node >= N_NODES) return;
    int lane = threadIdx.x & 63;
    int beg = off[node], end = off[node + 1];
    float a = 0.f;
    int i = beg;
    for (; i + 3 < end; i += 4) {
        int s0 = csr_src[i];
        int s1 = csr_src[i + 1];
        int s2 = csr_src[i + 2];
        int s3 = csr_src[i + 3];
        a += bf1(t2l[(long long)s0 * 64 + lane]) + bf1(t2l[(long long)s1 * 64 + lane])
           + bf1(t2l[(long long)s2 * 64 + lane]) + bf1(t2l[(long long)s3 * 64 + lane]);
    }
    for (; i < end; ++i) a += bf1(t2l[(long long)csr_src[i] * 64 + lane]);
    float inv = (end > beg) ? 1.0f / (float)(end - beg) : 0.f;
    float res = t2r[(long long)node * 64 + lane] + a * inv;
    z[(long long)node * 64 + lane] = f2bf(res);
}

// ---------------------------------------------------------------------------
// out[l] = dot(z[src_l], z[dst_l]) over 64 bf16 channels; 16 lanes per label
__global__ void edge_dot_kernel(const int* __restrict__ eli,
                                const unsigned short* __restrict__ z,
                                float* __restrict__ out) {
    long long gid = (long long)blockIdx.x * blockDim.x + threadIdx.x;
    int l = (int)(gid >> 4);
    int lane = (int)(gid & 15);
    if (l >= N_LABEL) return;
    int s = eli[l];
    int d = eli[N_LABEL + l];
    uint2 av = *reinterpret_cast<const uint2*>(z + (long long)s * 64 + lane * 4);
    uint2 bv = *reinterpret_cast<const uint2*>(z + (long long)d * 64 + lane * 4);
    float p = bf_lo(av.x) * bf_lo(bv.x) + bf_hi(av.x) * bf_hi(bv.x)
            + bf_lo(av.y) * bf_lo(bv.y) + bf_hi(av.y) * bf_hi(bv.y);
    p += __shfl_down(p, 8, 16);
    p += __shfl_down(p, 4, 16);
    p += __shfl_down(p, 2, 16);
    p += __shfl_down(p, 1, 16);
    if (lane == 0) out[l] = p;
}

// ---------------------------------------------------------------------------
extern "C" void kernel_launch(void* const* d_in, const int* in_sizes, int n_in,
                              void* d_out, int out_size, void* d_ws, size_t ws_size,
                              hipStream_t stream) {
    const float* x     = (const float*)d_in[0];
    const int*   ei    = (const int*)d_in[1];   // [2, 800000]: row0 src, row1 dst
    const int*   eli   = (const int*)d_in[2];   // [2, 200000]
    const float* W1l   = (const float*)d_in[3];
    const float* W1r   = (const float*)d_in[4];
    const float* b1    = (const float*)d_in[5];
    const float* gamma = (const float*)d_in[6];
    const float* beta  = (const float*)d_in[7];
    const float* W2l   = (const float*)d_in[8];
    const float* W2r   = (const float*)d_in[9];
    const float* b2    = (const float*)d_in[10];
    float* out = (float*)d_out;

    const int* src  = ei;
    const int* dstv = ei + N_EDGES;

    // workspace layout (ints first, then bf16/f32 regions; 16B-aligned)
    int* ideg  = (int*)d_ws;             // 50432 (zero-padded to NCHUNK*256)
    int* ioff  = ideg + 50432;           // 50056
    int* icur  = ioff + 50056;           // 50048
    int* ibsum = icur + 50048;           // 256
    int* iboff = ibsum + 256;            // 256
    int* icsr  = iboff + 256;            // 800000
    unsigned short* y1 = (unsigned short*)(icsr + 800000);  // 6.4M bf16 = 12.8 MB
    float* t2r = (float*)y1;                                // 3.2M f32 aliases y1 (y1 dead by gemm2)
    float* h   = (float*)(y1 + 6400000);                    // 6.4M f32 = 25.6 MB
    unsigned short* t2l = (unsigned short*)(h + 6400000);   // 3.2M bf16 = 6.4 MB
    unsigned short* z   = t2l + 3200000;                    // 3.2M bf16 = 6.4 MB
    float* sums = (float*)(z + 3200000);                    // 256
    float* ss   = sums + 256;                               // 256

    hipMemsetAsync(ideg, 0, 50432 * sizeof(int), stream);
    hipMemsetAsync(sums, 0, 256 * sizeof(float), stream);

    // ---- CSR build ----
    hist_kernel<<<(N_EDGES + 255) / 256, 256, 0, stream>>>(dstv, ideg);
    chunk_sum_kernel<<<NCHUNK, 256, 0, stream>>>(ideg, ibsum);
    scan_bsum_kernel<<<1, 256, 0, stream>>>(ibsum, iboff);
    scan_final_kernel<<<NCHUNK, 256, 0, stream>>>(ideg, iboff, ioff, icur);
    scatter_kernel<<<(N_EDGES + 255) / 256, 256, 0, stream>>>(src, dstv, icur, icsr);

    // ---- conv1: y1 = bf16(x@W1l), h = x@W1r + b1, then h += mean-gather(y1)
    gemm1_dual<<<(N_NODES + 31) / 32, 256, 0, stream>>>(x, W1l, W1r, b1, y1, h);
    agg_mean_add_128<<<(N_NODES + 3) / 4, 256, 0, stream>>>(
        ioff, icsr, (const unsigned*)y1, h);

    // ---- batchnorm stats (apply is fused into gemm2 staging) ----
    bn_stats_kernel<<<500, 256, 0, stream>>>(h, sums);
    bn_finalize_kernel<<<1, 128, 0, stream>>>(sums, gamma, beta, ss);

    // ---- conv2: t2l = bf16(relu(bn(h))@W2l), t2r = relu(bn(h))@W2r + b2 ----
    gemm2_dual<<<(N_NODES + 31) / 32, 256, 0, stream>>>(h, ss, W2l, W2r, b2, t2l, t2r);
    agg_mean_add_64<<<(N_NODES + 3) / 4, 256, 0, stream>>>(ioff, icsr, t2l, t2r, z);

    // ---- edge dot readout ----
    edge_dot_kernel<<<((long long)N_LABEL * 16 + 255) / 256, 256, 0, stream>>>(eli, z, out);
}

// Round 6
// 312.808 us; speedup vs baseline: 9.5397x; 1.1355x over previous
//
#include <hip/hip_runtime.h>

constexpr int N_NODES = 50000;
constexpr int IN_C    = 128;
constexpr int HID_C   = 128;
constexpr int OUT_C   = 64;
constexpr int N_EDGES = 800000;
constexpr int N_LABEL = 200000;
constexpr float BN_EPS = 1e-5f;
constexpr int NCHUNK  = (N_NODES + 256) / 256 + 1;   // 196 chunks cover 50176 >= 50001

typedef __attribute__((ext_vector_type(8))) short bf16x8;
typedef __attribute__((ext_vector_type(4))) float f32x4;

// ---- bf16 helpers (plain ushort storage) ----------------------------------
__device__ __forceinline__ float bf_lo(unsigned v) {
    union { unsigned u; float f; } t; t.u = v << 16; return t.f;
}
__device__ __forceinline__ float bf_hi(unsigned v) {
    union { unsigned u; float f; } t; t.u = v & 0xffff0000u; return t.f;
}
__device__ __forceinline__ float bf1(unsigned short u) {
    union { unsigned u; float f; } t; t.u = ((unsigned)u) << 16; return t.f;
}
__device__ __forceinline__ unsigned short f2bf(float f) {
    union { float f; unsigned u; } t; t.f = f;
    unsigned r = t.u + 0x7fffu + ((t.u >> 16) & 1u);   // round-nearest-even
    return (unsigned short)(r >> 16);
}

// ---------------------------------------------------------------------------
// CSR build step 1: histogram of dst
__global__ void hist_kernel(const int* __restrict__ dst, int* __restrict__ deg) {
    int e = blockIdx.x * blockDim.x + threadIdx.x;
    if (e < N_EDGES) atomicAdd(&deg[dst[e]], 1);
}

// CSR build step 2a: per-chunk sums (deg is zero-padded past N_NODES)
__global__ void chunk_sum_kernel(const int* __restrict__ deg, int* __restrict__ bsum) {
    int i = blockIdx.x * 256 + threadIdx.x;
    int v = deg[i];
    #pragma unroll
    for (int o = 32; o > 0; o >>= 1) v += __shfl_down(v, o, 64);
    __shared__ int ws[4];
    if ((threadIdx.x & 63) == 0) ws[threadIdx.x >> 6] = v;
    __syncthreads();
    if (threadIdx.x == 0) bsum[blockIdx.x] = ws[0] + ws[1] + ws[2] + ws[3];
}

// CSR build step 2b: exclusive scan of the chunk sums (single tiny block)
__global__ void scan_bsum_kernel(const int* __restrict__ bsum, int* __restrict__ boff) {
    __shared__ int t[256];
    int tid = threadIdx.x;
    t[tid] = (tid < NCHUNK) ? bsum[tid] : 0;
    __syncthreads();
    for (int o = 1; o < 256; o <<= 1) {
        int v = t[tid];
        int add = (tid >= o) ? t[tid - o] : 0;
        __syncthreads();
        t[tid] = v + add;
        __syncthreads();
    }
    boff[tid] = (tid == 0) ? 0 : t[tid - 1];
}

// CSR build step 2c: per-chunk exclusive scan + chunk offset -> off, cursor
__global__ void scan_final_kernel(const int* __restrict__ deg, const int* __restrict__ boff,
                                  int* __restrict__ off, int* __restrict__ cursor) {
    __shared__ int t[256];
    int tid = threadIdx.x;
    int i = blockIdx.x * 256 + tid;
    int d = deg[i];
    t[tid] = d;
    __syncthreads();
    for (int o = 1; o < 256; o <<= 1) {
        int v = t[tid];
        int add = (tid >= o) ? t[tid - o] : 0;
        __syncthreads();
        t[tid] = v + add;
        __syncthreads();
    }
    int excl = boff[blockIdx.x] + t[tid] - d;
    if (i <= N_NODES) {
        off[i] = excl;                     // off[N_NODES] == N_EDGES (deg pad = 0)
        if (i < N_NODES) cursor[i] = excl;
    }
}

// CSR build step 3: scatter src ids into csr order
__global__ void scatter_kernel(const int* __restrict__ src, const int* __restrict__ dst,
                               int* __restrict__ cursor, int* __restrict__ csr_src) {
    int e = blockIdx.x * blockDim.x + threadIdx.x;
    if (e < N_EDGES) {
        int pos = atomicAdd(&cursor[dst[e]], 1);
        csr_src[pos] = src[e];
    }
}

// ---------------------------------------------------------------------------
// MFMA GEMM: out[64 rows x C cols] = A(bf16-cast) @ [Wl | Wr]
//   MODE 0 (conv1): A = x (f32), C=256; cols 0..127 -> y1 (bf16),
//                   cols 128..255 -> h = . + b1 (f32)
//   MODE 1 (conv2): A = relu(h*ss0 + ss1) (fused BN), C=128;
//                   cols 0..63 -> t2l (bf16); cols 64..127 -> t2r = . + b2 (bf16)
// Fragment layouts (v_mfma_f32_16x16x32_bf16):
//   A: lane l, elem j <- A[m0 + (l&15)][kt*32 + (l>>4)*8 + j]
//   B: lane l, elem j <- B[kt*32 + (l>>4)*8 + j][nt*16 + (l&15)]  (pre-swizzled LDS)
//   D: lane l, reg  j -> D[m0 + (l>>4)*4 + j][nt*16 + (l&15)]     (verified m89/m91)
template <int MODE>
__global__ __launch_bounds__(256) void mfma_gemm(
    const float* __restrict__ A,
    const float* __restrict__ Wl, const float* __restrict__ Wr,
    const float* __restrict__ bias, const float* __restrict__ ss,
    unsigned short* __restrict__ outL,
    float* __restrict__ outHf, unsigned short* __restrict__ outHb)
{
    constexpr int C    = (MODE == 0) ? 256 : 128;
    constexpr int NT   = C / 16;
    constexpr int HALF = C / 2;
    __shared__ short sB[128 * C];    // 64 KB (MODE0) / 32 KB (MODE1)

    int tid = threadIdx.x;
    // ---- stage B (f32 global, coalesced) into bf16 fragment layout ----
    for (int i = tid; i < 128 * C; i += 256) {
        int k = (MODE == 0) ? (i >> 8) : (i >> 7);
        int n = (MODE == 0) ? (i & 255) : (i & 127);
        float v = (n < HALF) ? Wl[k * HALF + n] : Wr[k * HALF + (n - HALF)];
        int nt = n >> 4, nl = n & 15, kt = k >> 5, kk = k & 31;
        int l = ((kk >> 3) << 4) + nl, j = kk & 7;
        sB[(((nt << 2) + kt) * 64 + l) * 8 + j] = (short)f2bf(v);
    }
    __syncthreads();

    int wid = tid >> 6, lane = tid & 63;
    int m0 = blockIdx.x * 64 + wid * 16;
    int row = m0 + (lane & 15);
    int rowc = (row < N_NODES) ? row : (N_NODES - 1);
    const float* ap = A + (long long)rowc * 128;
    int kbase = (lane >> 4) * 8;

    bf16x8 a[4];
    #pragma unroll
    for (int kt = 0; kt < 4; ++kt) {
        int k0 = kt * 32 + kbase;
        float4 u0 = *reinterpret_cast<const float4*>(ap + k0);
        float4 u1 = *reinterpret_cast<const float4*>(ap + k0 + 4);
        float v[8] = {u0.x, u0.y, u0.z, u0.w, u1.x, u1.y, u1.z, u1.w};
        if (MODE == 1) {
            float4 s0 = *reinterpret_cast<const float4*>(ss + k0);
            float4 s1 = *reinterpret_cast<const float4*>(ss + k0 + 4);
            float4 t0 = *reinterpret_cast<const float4*>(ss + 128 + k0);
            float4 t1 = *reinterpret_cast<const float4*>(ss + 128 + k0 + 4);
            float sc[8] = {s0.x, s0.y, s0.z, s0.w, s1.x, s1.y, s1.z, s1.w};
            float sh[8] = {t0.x, t0.y, t0.z, t0.w, t1.x, t1.y, t1.z, t1.w};
            #pragma unroll
            for (int j = 0; j < 8; ++j) v[j] = fmaxf(v[j] * sc[j] + sh[j], 0.f);
        }
        #pragma unroll
        for (int j = 0; j < 8; ++j) a[kt][j] = (short)f2bf(v[j]);
    }

    f32x4 acc[NT] = {};
    #pragma unroll
    for (int kt = 0; kt < 4; ++kt) {
        #pragma unroll
        for (int nt = 0; nt < NT; ++nt) {
            bf16x8 b = *reinterpret_cast<const bf16x8*>(&sB[(((nt << 2) + kt) * 64 + lane) * 8]);
            acc[nt] = __builtin_amdgcn_mfma_f32_16x16x32_bf16(a[kt], b, acc[nt], 0, 0, 0);
        }
    }

    // ---- epilogue ----
    int r0 = m0 + ((lane >> 4) << 2);
    int nl = lane & 15;
    #pragma unroll
    for (int nt = 0; nt < NT; ++nt) {
        int col = nt * 16 + nl;
        float bb = (col >= HALF) ? bias[col - HALF] : 0.f;
        #pragma unroll
        for (int j = 0; j < 4; ++j) {
            int r = r0 + j;
            if (r >= N_NODES) continue;
            float vv = acc[nt][j];
            if (MODE == 0) {
                if (col < HALF) outL[(long long)r * 128 + col] = f2bf(vv);
                else            outHf[(long long)r * 128 + (col - HALF)] = vv + bb;
            } else {
                if (col < HALF) outL[(long long)r * 64 + col] = f2bf(vv);
                else            outHb[(long long)r * 64 + (col - HALF)] = f2bf(vv + bb);
            }
        }
    }
}

// ---------------------------------------------------------------------------
// conv1 aggregate: h[n] += mean_{s in N(n)} y1[s]  (y1 bf16-packed, 128 ch)
__global__ __launch_bounds__(256) void agg_mean_add_128(
    const int* __restrict__ off, const int* __restrict__ csr_src,
    const unsigned* __restrict__ ybf, float* __restrict__ h) {
    int node = blockIdx.x * 4 + (threadIdx.x >> 6);
    if (node >= N_NODES) return;
    int lane = threadIdx.x & 63;
    int beg = off[node], end = off[node + 1];
    float ax = 0.f, ay = 0.f;
    int i = beg;
    for (; i + 3 < end; i += 4) {
        int s0 = csr_src[i];
        int s1 = csr_src[i + 1];
        int s2 = csr_src[i + 2];
        int s3 = csr_src[i + 3];
        unsigned v0 = ybf[(long long)s0 * 64 + lane];
        unsigned v1 = ybf[(long long)s1 * 64 + lane];
        unsigned v2 = ybf[(long long)s2 * 64 + lane];
        unsigned v3 = ybf[(long long)s3 * 64 + lane];
        ax += bf_lo(v0) + bf_lo(v1) + bf_lo(v2) + bf_lo(v3);
        ay += bf_hi(v0) + bf_hi(v1) + bf_hi(v2) + bf_hi(v3);
    }
    for (; i < end; ++i) {
        unsigned v0 = ybf[(long long)csr_src[i] * 64 + lane];
        ax += bf_lo(v0); ay += bf_hi(v0);
    }
    float inv = (end > beg) ? 1.0f / (float)(end - beg) : 0.f;
    float2* hp = reinterpret_cast<float2*>(h + (long long)node * 128 + lane * 2);
    float2 hv = *hp;
    hv.x += ax * inv;
    hv.y += ay * inv;
    *hp = hv;
}

// ---------------------------------------------------------------------------
// BN stats: sums[c] = sum_r h[r][c], sums[128+c] = sum_r h[r][c]^2
__global__ void bn_stats_kernel(const float* __restrict__ h, float* __restrict__ sums) {
    int c = threadIdx.x & 127;
    int r0 = blockIdx.x * 2 + (threadIdx.x >> 7);
    int stride = gridDim.x * 2;
    float s = 0.f, sq = 0.f;
    for (int r = r0; r < N_NODES; r += stride) {
        float v = h[(long long)r * 128 + c];
        s += v;
        sq += v * v;
    }
    atomicAdd(&sums[c], s);
    atomicAdd(&sums[128 + c], sq);
}

// scale/shift: ss[c] = gamma*rsqrt(var+eps); ss[128+c] = beta - mu*scale
__global__ void bn_finalize_kernel(const float* __restrict__ sums,
                                   const float* __restrict__ gamma,
                                   const float* __restrict__ beta,
                                   float* __restrict__ ss) {
    int c = threadIdx.x;
    float mu  = sums[c] * (1.0f / N_NODES);
    float var = sums[128 + c] * (1.0f / N_NODES) - mu * mu;
    float sc = gamma[c] * rsqrtf(var + BN_EPS);
    ss[c] = sc;
    ss[128 + c] = beta[c] - mu * sc;
}

// ---------------------------------------------------------------------------
// conv2 aggregate: z[n] = bf16( mean_{s in N(n)} t2l[s] + t2r[n] )  (64 ch)
__global__ __launch_bounds__(256) void agg_mean_add_64(
    const int* __restrict__ off, const int* __restrict__ csr_src,
    const unsigned short* __restrict__ t2l, const unsigned short* __restrict__ t2r,
    unsigned short* __restrict__ z) {
    int node = blockIdx.x * 4 + (threadIdx.x >> 6);
    if (node >= N_NODES) return;
    int lane = threadIdx.x & 63;
    int beg = off[node], end = off[node + 1];
    float a = 0.f;
    int i = beg;
    for (; i + 3 < end; i += 4) {
        int s0 = csr_src[i];
        int s1 = csr_src[i + 1];
        int s2 = csr_src[i + 2];
        int s3 = csr_src[i + 3];
        a += bf1(t2l[(long long)s0 * 64 + lane]) + bf1(t2l[(long long)s1 * 64 + lane])
           + bf1(t2l[(long long)s2 * 64 + lane]) + bf1(t2l[(long long)s3 * 64 + lane]);
    }
    for (; i < end; ++i) a += bf1(t2l[(long long)csr_src[i] * 64 + lane]);
    float inv = (end > beg) ? 1.0f / (float)(end - beg) : 0.f;
    float res = bf1(t2r[(long long)node * 64 + lane]) + a * inv;
    z[(long long)node * 64 + lane] = f2bf(res);
}

// ---------------------------------------------------------------------------
// out[l] = dot(z[src_l], z[dst_l]) over 64 bf16 channels; 16 lanes per label
__global__ void edge_dot_kernel(const int* __restrict__ eli,
                                const unsigned short* __restrict__ z,
                                float* __restrict__ out) {
    long long gid = (long long)blockIdx.x * blockDim.x + threadIdx.x;
    int l = (int)(gid >> 4);
    int lane = (int)(gid & 15);
    if (l >= N_LABEL) return;
    int s = eli[l];
    int d = eli[N_LABEL + l];
    uint2 av = *reinterpret_cast<const uint2*>(z + (long long)s * 64 + lane * 4);
    uint2 bv = *reinterpret_cast<const uint2*>(z + (long long)d * 64 + lane * 4);
    float p = bf_lo(av.x) * bf_lo(bv.x) + bf_hi(av.x) * bf_hi(bv.x)
            + bf_lo(av.y) * bf_lo(bv.y) + bf_hi(av.y) * bf_hi(bv.y);
    p += __shfl_down(p, 8, 16);
    p += __shfl_down(p, 4, 16);
    p += __shfl_down(p, 2, 16);
    p += __shfl_down(p, 1, 16);
    if (lane == 0) out[l] = p;
}

// ---------------------------------------------------------------------------
extern "C" void kernel_launch(void* const* d_in, const int* in_sizes, int n_in,
                              void* d_out, int out_size, void* d_ws, size_t ws_size,
                              hipStream_t stream) {
    const float* x     = (const float*)d_in[0];
    const int*   ei    = (const int*)d_in[1];   // [2, 800000]: row0 src, row1 dst
    const int*   eli   = (const int*)d_in[2];   // [2, 200000]
    const float* W1l   = (const float*)d_in[3];
    const float* W1r   = (const float*)d_in[4];
    const float* b1    = (const float*)d_in[5];
    const float* gamma = (const float*)d_in[6];
    const float* beta  = (const float*)d_in[7];
    const float* W2l   = (const float*)d_in[8];
    const float* W2r   = (const float*)d_in[9];
    const float* b2    = (const float*)d_in[10];
    float* out = (float*)d_out;

    const int* src  = ei;
    const int* dstv = ei + N_EDGES;

    // workspace layout (ints first, then bf16/f32 regions; 16B-aligned)
    int* ideg  = (int*)d_ws;             // 50432 (zero-padded to NCHUNK*256)
    int* ioff  = ideg + 50432;           // 50056
    int* icur  = ioff + 50056;           // 50048
    int* ibsum = icur + 50048;           // 256
    int* iboff = ibsum + 256;            // 256
    int* icsr  = iboff + 256;            // 800000
    unsigned short* y1  = (unsigned short*)(icsr + 800000);  // 6.4M bf16
    float*          h   = (float*)(y1 + 6400000);            // 6.4M f32
    unsigned short* t2l = (unsigned short*)(h + 6400000);    // 3.2M bf16
    unsigned short* t2r = t2l + 3200000;                     // 3.2M bf16
    unsigned short* z   = t2r + 3200000;                     // 3.2M bf16
    float* sums = (float*)(z + 3200000);                     // 256
    float* ss   = sums + 256;                                // 256

    hipMemsetAsync(ideg, 0, 50432 * sizeof(int), stream);
    hipMemsetAsync(sums, 0, 256 * sizeof(float), stream);

    // ---- CSR build ----
    hist_kernel<<<(N_EDGES + 255) / 256, 256, 0, stream>>>(dstv, ideg);
    chunk_sum_kernel<<<NCHUNK, 256, 0, stream>>>(ideg, ibsum);
    scan_bsum_kernel<<<1, 256, 0, stream>>>(ibsum, iboff);
    scan_final_kernel<<<NCHUNK, 256, 0, stream>>>(ideg, iboff, ioff, icur);
    scatter_kernel<<<(N_EDGES + 255) / 256, 256, 0, stream>>>(src, dstv, icur, icsr);

    const int GEMM_GRID = (N_NODES + 63) / 64;   // 782

    // ---- conv1: [y1|h] = bf16mfma(x @ [W1l|W1r]), h gets +b1 ----
    mfma_gemm<0><<<GEMM_GRID, 256, 0, stream>>>(x, W1l, W1r, b1, ss, y1, h, nullptr);
    agg_mean_add_128<<<(N_NODES + 3) / 4, 256, 0, stream>>>(
        ioff, icsr, (const unsigned*)y1, h);

    // ---- batchnorm stats (apply is fused into gemm2 A-load) ----
    bn_stats_kernel<<<500, 256, 0, stream>>>(h, sums);
    bn_finalize_kernel<<<1, 128, 0, stream>>>(sums, gamma, beta, ss);

    // ---- conv2: [t2l|t2r] = bf16mfma(relu(bn(h)) @ [W2l|W2r]), t2r gets +b2 ----
    mfma_gemm<1><<<GEMM_GRID, 256, 0, stream>>>(h, W2l, W2r, b2, ss, t2l, nullptr, t2r);
    agg_mean_add_64<<<(N_NODES + 3) / 4, 256, 0, stream>>>(ioff, icsr, t2l, t2r, z);

    // ---- edge dot readout ----
    edge_dot_kernel<<<((long long)N_LABEL * 16 + 255) / 256, 256, 0, stream>>>(eli, z, out);
}